// Round 3
// baseline (142.122 us; speedup 1.0000x reference)
//
#include <hip/hip_runtime.h>

// Problem constants (from reference)
#define PP 4
#define QQ 16
#define NQ 128
#define HH 256
#define P5 1024   // PP^5

// ---------------------------------------------------------------------------
// Block-wide sum over 256 threads (4 waves). All threads return the total.
// ---------------------------------------------------------------------------
__device__ __forceinline__ float block_sum256(float v, float* red, int t) {
#pragma unroll
  for (int o = 32; o > 0; o >>= 1) v += __shfl_down(v, o, 64);
  if ((t & 63) == 0) red[t >> 6] = v;
  __syncthreads();
  float r = red[0] + red[1] + red[2] + red[3];
  __syncthreads();
  return r;
}

// ---------------------------------------------------------------------------
// Prep kernel — grid of HH=256 blocks, 256 threads each.
// Every block redundantly computes the tiny rhs vector (~80K FLOP) in LDS,
// then block hb computes its single w2r[hb] = dot(Wx2[hb,:], rhs) with a
// coalesced 4KB row read (spreads the 1MB Wx2 stream over 256 CUs).
// Block 0 additionally packs {Wx1, bx1} and computes b2r.
// Output layout in ws (stride 8 per h so main can use s_load_dwordx4):
//   ws[h*8 + {0,1,2,3,4}] = {Wx1[0][h], Wx1[1][h], Wx1[2][h], bx1[h], w2r[h]}
//   ws[2048] = b2r
// ---------------------------------------------------------------------------
__global__ __launch_bounds__(256) void prep_kernel(
    const float* __restrict__ eq,
    const float* __restrict__ q0, const float* __restrict__ q1,
    const float* __restrict__ q2, const float* __restrict__ q3,
    const float* __restrict__ q4,
    const float* __restrict__ Wx1, const float* __restrict__ bx1,
    const float* __restrict__ Wx2, const float* __restrict__ bx2,
    const float* __restrict__ Wq0, const float* __restrict__ bq0,
    const float* __restrict__ Wq1, const float* __restrict__ bq1,
    const float* __restrict__ Wq2, const float* __restrict__ bq2,
    const float* __restrict__ Wq3, const float* __restrict__ bq3,
    const float* __restrict__ Wq4, const float* __restrict__ bq4,
    float* __restrict__ ws) {
  __shared__ float red[4];
  __shared__ float sS[5][64];
  __shared__ float sRhs[P5];

  const int t = threadIdx.x;
  const int hb = blockIdx.x;  // the h this block owns
  const float eqv = eq[0];

  const float* qs[5]  = {q0, q1, q2, q3, q4};
  const float* Wqs[5] = {Wq0, Wq1, Wq2, Wq3, Wq4};
  const float* bqs[5] = {bq0, bq1, bq2, bq3, bq4};

  // A_i = sum_r y*qx, B_i = sum_r y, with y = exp(-qx^2 * eq)
  float A[5], B[5];
#pragma unroll
  for (int i = 0; i < 5; ++i) {
    float a = 0.f, b = 0.f;
    if (t < NQ) {
      float x = qs[i][t];
      float y = expf(-x * x * eqv);
      a = y * x;
      b = y;
    }
    A[i] = block_sum256(a, red, t);
    B[i] = block_sum256(b, red, t);
  }

  // s_i[j] = Wq_i[j]*A_i + bq_i[j]*B_i
  for (int k = t; k < 5 * 64; k += 256) {
    int i = k >> 6, j = k & 63;
    sS[i][j] = Wqs[i][j] * A[i] + bqs[i][j] * B[i];
  }
  __syncthreads();

  // rhs[idx] = sum_x s0[b,x] s1[d,x] s2[f,x] s3[m,x] s4[v,x]
  for (int idx = t; idx < P5; idx += 256) {
    int b = (idx >> 8) & 3, d = (idx >> 6) & 3, f = (idx >> 4) & 3,
        m = (idx >> 2) & 3, v = idx & 3;
    float s = 0.f;
#pragma unroll
    for (int x = 0; x < QQ; ++x)
      s += sS[0][b * QQ + x] * sS[1][d * QQ + x] * sS[2][f * QQ + x] *
           sS[3][m * QQ + x] * sS[4][v * QQ + x];
    sRhs[idx] = s;
  }
  __syncthreads();

  // w2r[hb] = dot(Wx2[hb,:], rhs): 4 elements per thread, block reduce.
  const float* wrow = Wx2 + hb * P5;
  float p = 0.f;
#pragma unroll
  for (int k = 0; k < 4; ++k)
    p = fmaf(wrow[t + 256 * k], sRhs[t + 256 * k], p);
  p = block_sum256(p, red, t);
  if (t == 0) ws[hb * 8 + 4] = p;

  if (hb == 0) {
    // pack Wx1 ([3][256] row-major) and bx1; zero the pad slots
    if (t < HH) {
      ws[t * 8 + 0] = Wx1[t];
      ws[t * 8 + 1] = Wx1[HH + t];
      ws[t * 8 + 2] = Wx1[2 * HH + t];
      ws[t * 8 + 3] = bx1[t];
      ws[t * 8 + 5] = 0.f;
      ws[t * 8 + 6] = 0.f;
      ws[t * 8 + 7] = 0.f;
    }
    // b2r = dot(bx2, rhs)
    float pb = 0.f;
    for (int j = t; j < P5; j += 256) pb = fmaf(bx2[j], sRhs[j], pb);
    pb = block_sum256(pb, red, t);
    if (t == 0) ws[HH * 8] = pb;
  }
}

// ---------------------------------------------------------------------------
// Main kernel: out[i] = sum_h tanh(b_h + x_i . W_h) * w2r[h] + b2r
// ONE ROW PER THREAD; every thread walks the full 256-entry packed table.
// The table address depends only on the loop induction variable and the
// SGPR kernel arg -> wave-UNIFORM -> backend emits s_load (scalar/SMEM
// pipe, one fetch per wave instead of 64 lane loads). No LDS, no barriers.
// 4 accumulators break the single fma dependence chain.
// ---------------------------------------------------------------------------
__global__ __launch_bounds__(64) void main_kernel(
    const float* __restrict__ input, const float* __restrict__ pk,
    float* __restrict__ out, int n) {
  const int row = blockIdx.x * 64 + threadIdx.x;
  const bool valid = row < n;

  float x0 = 0.f, x1 = 0.f, x2 = 0.f;
  if (valid) {
    x0 = input[row * 3 + 0];
    x1 = input[row * 3 + 1];
    x2 = input[row * 3 + 2];
  }

  float acc0 = 0.f, acc1 = 0.f, acc2 = 0.f, acc3 = 0.f;
#pragma unroll 8
  for (int h = 0; h < HH; h += 4) {
#pragma unroll
    for (int u = 0; u < 4; ++u) {
      const float w0 = pk[(h + u) * 8 + 0];
      const float w1 = pk[(h + u) * 8 + 1];
      const float w2 = pk[(h + u) * 8 + 2];
      const float b  = pk[(h + u) * 8 + 3];
      const float wr = pk[(h + u) * 8 + 4];
      float a = fmaf(x2, w2, fmaf(x1, w1, fmaf(x0, w0, b)));
      // tanh(a) = 1 - 2/(e^{2a}+1); saturates correctly for |a| large
      float ex = __expf(2.0f * a);
      float tnh = fmaf(-2.0f, __builtin_amdgcn_rcpf(ex + 1.0f), 1.0f);
      if (u == 0) acc0 = fmaf(tnh, wr, acc0);
      else if (u == 1) acc1 = fmaf(tnh, wr, acc1);
      else if (u == 2) acc2 = fmaf(tnh, wr, acc2);
      else acc3 = fmaf(tnh, wr, acc3);
    }
  }

  if (valid) out[row] = (acc0 + acc1) + (acc2 + acc3) + pk[HH * 8];
}

// ---------------------------------------------------------------------------
extern "C" void kernel_launch(void* const* d_in, const int* in_sizes, int n_in,
                              void* d_out, int out_size, void* d_ws,
                              size_t ws_size, hipStream_t stream) {
  const float* input = (const float*)d_in[0];
  const float* eq    = (const float*)d_in[1];
  const float* q0    = (const float*)d_in[2];
  const float* q1    = (const float*)d_in[3];
  const float* q2    = (const float*)d_in[4];
  const float* q3    = (const float*)d_in[5];
  const float* q4    = (const float*)d_in[6];
  const float* Wx1   = (const float*)d_in[7];
  const float* bx1   = (const float*)d_in[8];
  const float* Wx2   = (const float*)d_in[9];
  const float* bx2   = (const float*)d_in[10];
  const float* Wq0   = (const float*)d_in[11];
  const float* bq0   = (const float*)d_in[12];
  const float* Wq1   = (const float*)d_in[13];
  const float* bq1   = (const float*)d_in[14];
  const float* Wq2   = (const float*)d_in[15];
  const float* bq2   = (const float*)d_in[16];
  const float* Wq3   = (const float*)d_in[17];
  const float* bq3   = (const float*)d_in[18];
  const float* Wq4   = (const float*)d_in[19];
  const float* bq4   = (const float*)d_in[20];

  float* ws  = (float*)d_ws;
  float* out = (float*)d_out;
  const int n = in_sizes[0] / 3;  // N = 100000

  hipLaunchKernelGGL(prep_kernel, dim3(HH), dim3(256), 0, stream,
                     eq, q0, q1, q2, q3, q4, Wx1, bx1, Wx2, bx2,
                     Wq0, bq0, Wq1, bq1, Wq2, bq2, Wq3, bq3, Wq4, bq4, ws);

  const int blocks = (n + 63) / 64;  // one row per thread, 64-thread blocks
  hipLaunchKernelGGL(main_kernel, dim3(blocks), dim3(64), 0, stream,
                     input, ws, out, n);
}

// Round 4
// 119.609 us; speedup vs baseline: 1.1882x; 1.1882x over previous
//
#include <hip/hip_runtime.h>

// Problem constants (from reference)
#define QQ 16
#define NQ 128
#define HH 256
#define P5 1024   // 4^5
#define LOG2E   1.44269504088896340f
#define K2LOG2E 2.88539008177792681f  // 2*log2(e)

// ---------------------------------------------------------------------------
// Block-wide sum over 256 threads (4 waves). All threads return the total.
// ---------------------------------------------------------------------------
__device__ __forceinline__ float block_sum256(float v, float* red, int t) {
#pragma unroll
  for (int o = 32; o > 0; o >>= 1) v += __shfl_down(v, o, 64);
  if ((t & 63) == 0) red[t >> 6] = v;
  __syncthreads();
  float r = red[0] + red[1] + red[2] + red[3];
  __syncthreads();
  return r;
}

// ---------------------------------------------------------------------------
// Prep kernel — 256 blocks x 256 threads. Every block redundantly computes
// the tiny rhs vector in LDS (a few us of parallel work), then block hb
// computes w2r[hb] = dot(Wx2[hb,:], rhs) with a coalesced 4KB row read.
// Output: ws[h] = w2r[h] (h<256); ws[256] = b2r = dot(bx2, rhs).
// A/B reduction uses per-wave shuffle partials -> 2 barriers total (the old
// block_sum256 version paid 20 barriers here).
// ---------------------------------------------------------------------------
__global__ __launch_bounds__(256) void prep_kernel(
    const float* __restrict__ eq,
    const float* __restrict__ q0, const float* __restrict__ q1,
    const float* __restrict__ q2, const float* __restrict__ q3,
    const float* __restrict__ q4,
    const float* __restrict__ Wx2, const float* __restrict__ bx2,
    const float* __restrict__ Wq0, const float* __restrict__ bq0,
    const float* __restrict__ Wq1, const float* __restrict__ bq1,
    const float* __restrict__ Wq2, const float* __restrict__ bq2,
    const float* __restrict__ Wq3, const float* __restrict__ bq3,
    const float* __restrict__ Wq4, const float* __restrict__ bq4,
    float* __restrict__ ws) {
  __shared__ float sS[5][64];
  __shared__ float sRhs[P5];
  __shared__ float sPart[4][10];
  __shared__ float sAB[10];
  __shared__ float red[4];

  const int t = threadIdx.x;
  const int hb = blockIdx.x;
  const float c = -eq[0] * LOG2E;  // y = exp(-x^2*eq) = exp2(x^2 * c)

  const float* qs[5]  = {q0, q1, q2, q3, q4};
  const float* Wqs[5] = {Wq0, Wq1, Wq2, Wq3, Wq4};
  const float* bqs[5] = {bq0, bq1, bq2, bq3, bq4};

  // A_i = sum_r y*qx (v[2i]), B_i = sum_r y (v[2i+1])
  float v[10];
#pragma unroll
  for (int i = 0; i < 5; ++i) {
    float a = 0.f, b = 0.f;
    if (t < NQ) {
      float x = qs[i][t];
      float y = exp2f(x * x * c);
      a = y * x;
      b = y;
    }
    v[2 * i] = a;
    v[2 * i + 1] = b;
  }
#pragma unroll
  for (int k = 0; k < 10; ++k) {
    float s = v[k];
#pragma unroll
    for (int o = 32; o > 0; o >>= 1) s += __shfl_down(s, o, 64);
    if ((t & 63) == 0) sPart[t >> 6][k] = s;
  }
  __syncthreads();
  if (t < 10) sAB[t] = sPart[0][t] + sPart[1][t] + sPart[2][t] + sPart[3][t];
  __syncthreads();

  // s_i[j] = Wq_i[j]*A_i + bq_i[j]*B_i   (5 x 64)
  for (int k = t; k < 5 * 64; k += 256) {
    int i = k >> 6, j = k & 63;
    sS[i][j] = Wqs[i][j] * sAB[2 * i] + bqs[i][j] * sAB[2 * i + 1];
  }
  __syncthreads();

  // rhs[idx] = sum_x s0[b,x] s1[d,x] s2[f,x] s3[m,x] s4[v,x]
  for (int idx = t; idx < P5; idx += 256) {
    int b = (idx >> 8) & 3, d = (idx >> 6) & 3, f = (idx >> 4) & 3,
        m = (idx >> 2) & 3, w = idx & 3;
    float s = 0.f;
#pragma unroll
    for (int x = 0; x < QQ; ++x)
      s += sS[0][b * QQ + x] * sS[1][d * QQ + x] * sS[2][f * QQ + x] *
           sS[3][m * QQ + x] * sS[4][w * QQ + x];
    sRhs[idx] = s;
  }
  __syncthreads();

  // w2r[hb] = dot(Wx2[hb,:], rhs)
  const float* wrow = Wx2 + hb * P5;
  float p = 0.f;
#pragma unroll
  for (int k = 0; k < 4; ++k)
    p = fmaf(wrow[t + 256 * k], sRhs[t + 256 * k], p);
  p = block_sum256(p, red, t);
  if (t == 0) ws[hb] = p;

  if (hb == 0) {
    float pb = 0.f;
    for (int j = t; j < P5; j += 256) pb = fmaf(bx2[j], sRhs[j], pb);
    pb = block_sum256(pb, red, t);
    if (t == 0) ws[HH] = pb;
  }
}

// ---------------------------------------------------------------------------
// Main kernel: out[i] = sum_h w2r[h]*tanh(b_h + x_i.W_h) + b2r
// Refactor: tanh = 1 - 2/(e^{2a}+1)  ->  out = (Sum w2r + b2r)
//            + sum_h (-2*w2r[h]) / (1 + exp2(K2LOG2E*(x.W_h + b_h)))
// Table staged once per block into LDS:
//   qtab[h] = K2LOG2E * {Wx1[0][h], Wx1[1][h], Wx1[2][h], bx1[h]}  (float4)
//   wtab[h] = -2 * w2r[h]                                          (float)
// Per h per wave: 1 broadcast ds_read_b128 + 1/4 ds_read_b128.
// Grid: 196 blocks x 256 threads; each thread carries R=2 rows so the
// table walk is amortized and the two rows give independent exp/rcp chains.
// ---------------------------------------------------------------------------
__global__ __launch_bounds__(256) void main_kernel(
    const float* __restrict__ input, const float* __restrict__ Wx1,
    const float* __restrict__ bx1, const float* __restrict__ wsv,
    float* __restrict__ out, int n) {
  __shared__ float4 qtab[HH];
  __shared__ float4 wtabv[HH / 4];
  __shared__ float red[4];

  const int t = threadIdx.x;

  // ---- stage tables (one element per thread, coalesced) ----
  float w2r = wsv[t];
  qtab[t] = make_float4(K2LOG2E * Wx1[t], K2LOG2E * Wx1[HH + t],
                        K2LOG2E * Wx1[2 * HH + t], K2LOG2E * bx1[t]);
  ((float*)wtabv)[t] = -2.0f * w2r;

  // block-reduce Sum w2r (folds the "+1" of tanh into a single constant)
  float s = w2r;
#pragma unroll
  for (int o = 32; o > 0; o >>= 1) s += __shfl_down(s, o, 64);
  if ((t & 63) == 0) red[t >> 6] = s;
  __syncthreads();  // covers qtab/wtab/red
  const float CONST = red[0] + red[1] + red[2] + red[3] + wsv[HH];

  // ---- two rows per thread ----
  const int rA = blockIdx.x * 512 + t;
  const int rB = rA + 256;
  const bool vA = rA < n, vB = rB < n;
  float xa0 = 0.f, xa1 = 0.f, xa2 = 0.f;
  float xb0 = 0.f, xb1 = 0.f, xb2 = 0.f;
  if (vA) { xa0 = input[rA * 3]; xa1 = input[rA * 3 + 1]; xa2 = input[rA * 3 + 2]; }
  if (vB) { xb0 = input[rB * 3]; xb1 = input[rB * 3 + 1]; xb2 = input[rB * 3 + 2]; }

  float accA = 0.f, accB = 0.f;
#pragma unroll 4
  for (int h4 = 0; h4 < HH / 4; ++h4) {
    const float4 wq = wtabv[h4];
    const float wrv[4] = {wq.x, wq.y, wq.z, wq.w};
#pragma unroll
    for (int u = 0; u < 4; ++u) {
      const float4 q = qtab[h4 * 4 + u];
      float aA = fmaf(q.z, xa2, fmaf(q.y, xa1, fmaf(q.x, xa0, q.w)));
      float aB = fmaf(q.z, xb2, fmaf(q.y, xb1, fmaf(q.x, xb0, q.w)));
      float eA = exp2f(aA);          // = e^{2a} (log2e folded into weights)
      float eB = exp2f(aB);
      float rA_ = __builtin_amdgcn_rcpf(eA + 1.0f);  // inf -> 0, ok
      float rB_ = __builtin_amdgcn_rcpf(eB + 1.0f);
      accA = fmaf(wrv[u], rA_, accA);
      accB = fmaf(wrv[u], rB_, accB);
    }
  }

  if (vA) out[rA] = accA + CONST;
  if (vB) out[rB] = accB + CONST;
}

// ---------------------------------------------------------------------------
extern "C" void kernel_launch(void* const* d_in, const int* in_sizes, int n_in,
                              void* d_out, int out_size, void* d_ws,
                              size_t ws_size, hipStream_t stream) {
  const float* input = (const float*)d_in[0];
  const float* eq    = (const float*)d_in[1];
  const float* q0    = (const float*)d_in[2];
  const float* q1    = (const float*)d_in[3];
  const float* q2    = (const float*)d_in[4];
  const float* q3    = (const float*)d_in[5];
  const float* q4    = (const float*)d_in[6];
  const float* Wx1   = (const float*)d_in[7];
  const float* bx1   = (const float*)d_in[8];
  const float* Wx2   = (const float*)d_in[9];
  const float* bx2   = (const float*)d_in[10];
  const float* Wq0   = (const float*)d_in[11];
  const float* bq0   = (const float*)d_in[12];
  const float* Wq1   = (const float*)d_in[13];
  const float* bq1   = (const float*)d_in[14];
  const float* Wq2   = (const float*)d_in[15];
  const float* bq2   = (const float*)d_in[16];
  const float* Wq3   = (const float*)d_in[17];
  const float* bq3   = (const float*)d_in[18];
  const float* Wq4   = (const float*)d_in[19];
  const float* bq4   = (const float*)d_in[20];

  float* ws  = (float*)d_ws;
  float* out = (float*)d_out;
  const int n = in_sizes[0] / 3;  // N = 100000

  hipLaunchKernelGGL(prep_kernel, dim3(HH), dim3(256), 0, stream,
                     eq, q0, q1, q2, q3, q4, Wx2, bx2,
                     Wq0, bq0, Wq1, bq1, Wq2, bq2, Wq3, bq3, Wq4, bq4, ws);

  const int blocks = (n + 511) / 512;  // 512 rows per block (R=2 per thread)
  hipLaunchKernelGGL(main_kernel, dim3(blocks), dim3(256), 0, stream,
                     input, Wx1, bx1, ws, out, n);
}